// Round 1
// baseline (191.537 us; speedup 1.0000x reference)
//
#include <hip/hip_runtime.h>
#include <stdint.h>
#include <stddef.h>

#define TB 2048
#define KDIM 1024
#define NH 16
#define HD 64

typedef __attribute__((ext_vector_type(8))) __bf16 bf16x8;
typedef __attribute__((ext_vector_type(4))) float f32x4;
typedef __attribute__((ext_vector_type(8))) unsigned short u16x8;

static __device__ __forceinline__ unsigned short f2bf(float f) {
  unsigned u = __builtin_bit_cast(unsigned, f);
  return (unsigned short)((u + 0x7FFFu + ((u >> 16) & 1u)) >> 16);
}

static __device__ __forceinline__ bf16x8 ld_frag(const unsigned short* p) {
  u16x8 v = *(const u16x8*)p;
  return __builtin_bit_cast(bf16x8, v);
}

// global(16B per lane) -> LDS, linear lane order. LDS ptr must be wave-uniform.
static __device__ __forceinline__ void gload_lds16(const void* g, void* l) {
  auto gp = (const __attribute__((address_space(1))) unsigned int*)(uintptr_t)g;
  auto lp = (__attribute__((address_space(3))) unsigned int*)(unsigned int)(uintptr_t)l;
  __builtin_amdgcn_global_load_lds(gp, lp, 16, 0, 0);
}

static __device__ __forceinline__ float redmax16(float v) {
  v = fmaxf(v, __shfl_xor(v, 1));
  v = fmaxf(v, __shfl_xor(v, 2));
  v = fmaxf(v, __shfl_xor(v, 4));
  v = fmaxf(v, __shfl_xor(v, 8));
  return v;
}
static __device__ __forceinline__ float redsum16(float v) {
  v += __shfl_xor(v, 1);
  v += __shfl_xor(v, 2);
  v += __shfl_xor(v, 4);
  v += __shfl_xor(v, 8);
  return v;
}

// ---------------- f32 -> bf16 convert (8 elems/thread) ----------------
__global__ void k_cvt(const float* __restrict__ in, unsigned short* __restrict__ out, int n8) {
  int i = blockIdx.x * blockDim.x + threadIdx.x;
  if (i >= n8) return;
  const float4* p = (const float4*)in + (size_t)i * 2;
  float4 a = p[0], b = p[1];
  u16x8 o;
  o[0] = f2bf(a.x); o[1] = f2bf(a.y); o[2] = f2bf(a.z); o[3] = f2bf(a.w);
  o[4] = f2bf(b.x); o[5] = f2bf(b.y); o[6] = f2bf(b.z); o[7] = f2bf(b.w);
  *((u16x8*)out + i) = o;
}

// ---------------- GEMM C = A @ W^T (A:[M,K] bf16, W:[N,K] bf16) ----------------
// 128x128 tile, BK=32, 4 waves (2x2), 16x16x32 MFMA, 4x4 frags/wave.
template <int MODE>  // 0: bf16 out, 1: f32 out + bias
static __device__ __forceinline__ void gemm_body(
    const unsigned short* __restrict__ A, const unsigned short* __restrict__ W,
    unsigned short* __restrict__ Cb, float* __restrict__ Cf,
    const float* __restrict__ bias, int by, int bx,
    unsigned short* As, unsigned short* Bs) {
  const int K = KDIM, N = KDIM;
  int tid = threadIdx.x, lane = tid & 63, wid = tid >> 6;
  int r = lane & 15, g = lane >> 4;
  int wm = wid >> 1, wn = wid & 1;

  f32x4 acc[4][4];
#pragma unroll
  for (int m = 0; m < 4; ++m)
#pragma unroll
    for (int n = 0; n < 4; ++n) acc[m][n] = (f32x4){0.f, 0.f, 0.f, 0.f};

  const unsigned short* Ag = A + (size_t)(by * 128) * K;
  const unsigned short* Wg = W + (size_t)(bx * 128) * K;

  for (int k0 = 0; k0 < K; k0 += 32) {
#pragma unroll
    for (int it = 0; it < 2; ++it) {
      int base = it * 256 + wid * 64;  // wave-uniform chunk base
      int c = base + lane;             // chunk 0..511; row=c>>2, colchunk=c&3
      gload_lds16(Ag + (size_t)(c >> 2) * K + k0 + (c & 3) * 8, &As[base * 8]);
      gload_lds16(Wg + (size_t)(c >> 2) * K + k0 + (c & 3) * 8, &Bs[base * 8]);
    }
    __syncthreads();
    bf16x8 af[4], bf[4];
#pragma unroll
    for (int m = 0; m < 4; ++m) af[m] = ld_frag(&As[(wm * 64 + m * 16 + r) * 32 + g * 8]);
#pragma unroll
    for (int n = 0; n < 4; ++n) bf[n] = ld_frag(&Bs[(wn * 64 + n * 16 + r) * 32 + g * 8]);
#pragma unroll
    for (int m = 0; m < 4; ++m)
#pragma unroll
      for (int n = 0; n < 4; ++n)
        acc[m][n] = __builtin_amdgcn_mfma_f32_16x16x32_bf16(af[m], bf[n], acc[m][n], 0, 0, 0);
    __syncthreads();
  }

#pragma unroll
  for (int m = 0; m < 4; ++m)
#pragma unroll
    for (int n = 0; n < 4; ++n) {
      int col = bx * 128 + wn * 64 + n * 16 + r;
#pragma unroll
      for (int j = 0; j < 4; ++j) {
        int row = by * 128 + wm * 64 + m * 16 + g * 4 + j;
        if (MODE == 0)
          Cb[(size_t)row * N + col] = f2bf(acc[m][n][j]);
        else
          Cf[(size_t)row * N + col] = acc[m][n][j] + bias[col];
      }
    }
}

__global__ __launch_bounds__(256) void k_gemm_qkv(
    const unsigned short* __restrict__ X,
    const unsigned short* __restrict__ Wq, const unsigned short* __restrict__ Wk,
    const unsigned short* __restrict__ Wv,
    unsigned short* __restrict__ Q, unsigned short* __restrict__ Kp,
    unsigned short* __restrict__ V) {
  __shared__ __align__(16) unsigned short As[4096];
  __shared__ __align__(16) unsigned short Bs[4096];
  int idx = blockIdx.x;            // 32 * 24
  int by = idx / 24, bxx = idx % 24;
  int which = bxx >> 3, bx = bxx & 7;
  const unsigned short* W = (which == 0) ? Wq : (which == 1) ? Wk : Wv;
  unsigned short* C = (which == 0) ? Q : (which == 1) ? Kp : V;
  gemm_body<0>(X, W, C, nullptr, nullptr, by, bx, As, Bs);
}

__global__ __launch_bounds__(256) void k_gemm_out(
    const unsigned short* __restrict__ AO, const unsigned short* __restrict__ Wo,
    float* __restrict__ out, const float* __restrict__ bias) {
  __shared__ __align__(16) unsigned short As[4096];
  __shared__ __align__(16) unsigned short Bs[4096];
  int by = blockIdx.x >> 3, bx = blockIdx.x & 7;
  gemm_body<1>(AO, Wo, nullptr, out, bias, by, bx, As, Bs);
}

// ---------------- V [b,t,h*64+d] -> Vt [b,h,d,t] ----------------
__global__ __launch_bounds__(256) void k_transpose_v(
    const unsigned short* __restrict__ V, unsigned short* __restrict__ Vt) {
  int tt = blockIdx.x & 31, bh = blockIdx.x >> 5;
  int b = bh >> 4, h = bh & 15;
  __shared__ __align__(16) unsigned short ls[64][72];
  int tid = threadIdx.x;
#pragma unroll
  for (int it = 0; it < 2; ++it) {
    int c = it * 256 + tid;
    int t = c >> 3, d0 = (c & 7) * 8;
    const unsigned short* src = V + ((size_t)(b * TB + tt * 64 + t)) * KDIM + h * HD + d0;
    *(u16x8*)&ls[t][d0] = *(const u16x8*)src;
  }
  __syncthreads();
#pragma unroll
  for (int it = 0; it < 2; ++it) {
    int c = it * 256 + tid;
    int d = c >> 3, t0 = (c & 7) * 8;
    u16x8 v;
#pragma unroll
    for (int j = 0; j < 8; ++j) v[j] = ls[t0 + j][d];
    unsigned short* dst = Vt + ((size_t)(bh * HD + d)) * TB + tt * 64 + t0;
    *(u16x8*)dst = v;
  }
}

// ---------------- flash attention ----------------
// grid: b*h*(T/64) blocks, 256 threads (4 waves). Wave w owns 16 Q rows.
// K tile [64 keys][64 dims], Vt tile [64 dims][64 keys] staged in LDS with
// XOR swizzle (16B block ^= row&7), applied on the pre-swizzled global source.
__global__ __launch_bounds__(256) void k_attn(
    const unsigned short* __restrict__ Q, const unsigned short* __restrict__ Kp,
    const unsigned short* __restrict__ Vt, unsigned short* __restrict__ AO) {
  __shared__ __align__(16) unsigned short Ks[64 * 64];
  __shared__ __align__(16) unsigned short Vs[64 * 64];
  __shared__ __align__(16) unsigned short Ps[4][16 * 64];

  int qt = blockIdx.x & 31, bh = blockIdx.x >> 5;
  int b = bh >> 4, h = bh & 15;
  int tid = threadIdx.x, lane = tid & 63, w = tid >> 6;
  int r = lane & 15, g = lane >> 4;

  // Q fragments (A operand), read once from global
  const unsigned short* Qp = Q + ((size_t)(b * TB + qt * 64 + w * 16 + r)) * KDIM + h * HD;
  bf16x8 aq0 = ld_frag(&Qp[g * 8]);
  bf16x8 aq1 = ld_frag(&Qp[32 + g * 8]);

  f32x4 o[4];
#pragma unroll
  for (int n = 0; n < 4; ++n) o[n] = (f32x4){0.f, 0.f, 0.f, 0.f};
  float m_run[4] = {-1e30f, -1e30f, -1e30f, -1e30f};
  float l_run[4] = {0.f, 0.f, 0.f, 0.f};

  const unsigned short* Kbase = Kp + (size_t)(b * TB) * KDIM + h * HD;
  const unsigned short* Vbase = Vt + (size_t)bh * HD * TB;
  unsigned short* Pw = &Ps[w][0];

  for (int kt = 0; kt < TB / 64; ++kt) {
    // stage K and Vt tiles (swizzled content via pre-swizzled global source)
#pragma unroll
    for (int it = 0; it < 2; ++it) {
      int base = it * 256 + w * 64;
      int c = base + lane;            // 0..511
      int rr = c >> 3;                // tile row
      int blk = (c & 7) ^ (rr & 7);   // source 16B block for this LDS slot
      gload_lds16(Kbase + (size_t)(kt * 64 + rr) * KDIM + blk * 8, &Ks[base * 8]);
      gload_lds16(Vbase + (size_t)rr * TB + kt * 64 + blk * 8, &Vs[base * 8]);
    }
    __syncthreads();

    // S = Q @ Ktile^T  (4 col frags of 16 keys each)
    f32x4 s[4];
#pragma unroll
    for (int n = 0; n < 4; ++n) {
      int row = n * 16 + r;
      int b0 = (0 * 4 + g) ^ (row & 7);
      int b1 = (1 * 4 + g) ^ (row & 7);
      bf16x8 kf0 = ld_frag(&Ks[row * 64 + b0 * 8]);
      bf16x8 kf1 = ld_frag(&Ks[row * 64 + b1 * 8]);
      f32x4 z = (f32x4){0.f, 0.f, 0.f, 0.f};
      z = __builtin_amdgcn_mfma_f32_16x16x32_bf16(aq0, kf0, z, 0, 0, 0);
      z = __builtin_amdgcn_mfma_f32_16x16x32_bf16(aq1, kf1, z, 0, 0, 0);
      s[n] = z;
    }

    // online softmax per row (row = g*4 + j, spread over 16 lanes' cols)
#pragma unroll
    for (int j = 0; j < 4; ++j) {
      float s0 = s[0][j] * 0.125f, s1 = s[1][j] * 0.125f;
      float s2 = s[2][j] * 0.125f, s3 = s[3][j] * 0.125f;
      float mx = redmax16(fmaxf(fmaxf(s0, s1), fmaxf(s2, s3)));
      float mnew = fmaxf(m_run[j], mx);
      float sc = __expf(m_run[j] - mnew);
      m_run[j] = mnew;
      float p0 = __expf(s0 - mnew), p1 = __expf(s1 - mnew);
      float p2 = __expf(s2 - mnew), p3 = __expf(s3 - mnew);
      s[0][j] = p0; s[1][j] = p1; s[2][j] = p2; s[3][j] = p3;
      float rs = redsum16(p0 + p1 + p2 + p3);
      l_run[j] = l_run[j] * sc + rs;
#pragma unroll
      for (int n = 0; n < 4; ++n) o[n][j] *= sc;
    }

    // P -> LDS (bf16, swizzled), then PV
#pragma unroll
    for (int j = 0; j < 4; ++j) {
      int prow = g * 4 + j;
#pragma unroll
      for (int n = 0; n < 4; ++n) {
        int col = n * 16 + r;
        int blk = (col >> 3) ^ (prow & 7);
        Pw[prow * 64 + blk * 8 + (col & 7)] = f2bf(s[n][j]);
      }
    }
    int pb0 = (0 * 4 + g) ^ (r & 7);
    int pb1 = (1 * 4 + g) ^ (r & 7);
    bf16x8 pa0 = ld_frag(&Pw[r * 64 + pb0 * 8]);
    bf16x8 pa1 = ld_frag(&Pw[r * 64 + pb1 * 8]);
#pragma unroll
    for (int n = 0; n < 4; ++n) {
      int vrow = n * 16 + r;
      int vb0 = (0 * 4 + g) ^ (vrow & 7);
      int vb1 = (1 * 4 + g) ^ (vrow & 7);
      bf16x8 vf0 = ld_frag(&Vs[vrow * 64 + vb0 * 8]);
      bf16x8 vf1 = ld_frag(&Vs[vrow * 64 + vb1 * 8]);
      o[n] = __builtin_amdgcn_mfma_f32_16x16x32_bf16(pa0, vf0, o[n], 0, 0, 0);
      o[n] = __builtin_amdgcn_mfma_f32_16x16x32_bf16(pa1, vf1, o[n], 0, 0, 0);
    }
    __syncthreads();
  }

  // epilogue: normalize and store bf16
#pragma unroll
  for (int n = 0; n < 4; ++n)
#pragma unroll
    for (int j = 0; j < 4; ++j) {
      int row = qt * 64 + w * 16 + g * 4 + j;
      AO[((size_t)(b * TB + row)) * KDIM + h * HD + n * 16 + r] = f2bf(o[n][j] / l_run[j]);
    }
}

// ---------------- launch ----------------
extern "C" void kernel_launch(void* const* d_in, const int* in_sizes, int n_in,
                              void* d_out, int out_size, void* d_ws, size_t ws_size,
                              hipStream_t stream) {
  const float* x  = (const float*)d_in[0];
  const float* Wq = (const float*)d_in[1];
  const float* Wk = (const float*)d_in[2];
  const float* Wv = (const float*)d_in[3];
  const float* Wo = (const float*)d_in[4];
  const float* bo = (const float*)d_in[5];

  char* ws = (char*)d_ws;
  const size_t MB = 1 << 20;
  unsigned short* xb  = (unsigned short*)(ws + 0 * MB);   // 8 MiB
  unsigned short* wqb = (unsigned short*)(ws + 8 * MB);   // 2 MiB
  unsigned short* wkb = (unsigned short*)(ws + 10 * MB);
  unsigned short* wvb = (unsigned short*)(ws + 12 * MB);
  unsigned short* wob = (unsigned short*)(ws + 14 * MB);
  unsigned short* Qb  = (unsigned short*)(ws + 16 * MB);  // 8 MiB
  unsigned short* Kb  = (unsigned short*)(ws + 24 * MB);
  unsigned short* Vb  = (unsigned short*)(ws + 32 * MB);
  unsigned short* Vtb = (unsigned short*)(ws + 40 * MB);
  unsigned short* AOb = (unsigned short*)(ws + 48 * MB);  // ends at 56 MiB

  k_cvt<<<2048, 256, 0, stream>>>(x, xb, (2 * TB * KDIM) / 8);
  k_cvt<<<512, 256, 0, stream>>>(Wq, wqb, (KDIM * KDIM) / 8);
  k_cvt<<<512, 256, 0, stream>>>(Wk, wkb, (KDIM * KDIM) / 8);
  k_cvt<<<512, 256, 0, stream>>>(Wv, wvb, (KDIM * KDIM) / 8);
  k_cvt<<<512, 256, 0, stream>>>(Wo, wob, (KDIM * KDIM) / 8);

  k_gemm_qkv<<<32 * 24, 256, 0, stream>>>(xb, wqb, wkb, wvb, Qb, Kb, Vb);
  k_transpose_v<<<1024, 256, 0, stream>>>(Vb, Vtb);
  k_attn<<<1024, 256, 0, stream>>>(Qb, Kb, Vtb, AOb);
  k_gemm_out<<<256, 256, 0, stream>>>(AOb, wob, (float*)d_out, bo);
}

// Round 2
// 160.069 us; speedup vs baseline: 1.1966x; 1.1966x over previous
//
#include <hip/hip_runtime.h>
#include <stdint.h>
#include <stddef.h>

#define TB 2048
#define KDIM 1024
#define NH 16
#define HD 64

typedef __attribute__((ext_vector_type(8))) __bf16 bf16x8;
typedef __attribute__((ext_vector_type(4))) float f32x4;
typedef __attribute__((ext_vector_type(16))) float f32x16;
typedef __attribute__((ext_vector_type(8))) unsigned short u16x8;

static __device__ __forceinline__ unsigned short f2bf(float f) {
  unsigned u = __builtin_bit_cast(unsigned, f);
  return (unsigned short)((u + 0x7FFFu + ((u >> 16) & 1u)) >> 16);
}

static __device__ __forceinline__ unsigned pack_bf(float a, float b) {
  return (unsigned)f2bf(a) | ((unsigned)f2bf(b) << 16);
}

static __device__ __forceinline__ bf16x8 ld_frag(const unsigned short* p) {
  u16x8 v = *(const u16x8*)p;
  return __builtin_bit_cast(bf16x8, v);
}

// global(16B per lane) -> LDS, linear lane order. LDS ptr must be wave-uniform.
static __device__ __forceinline__ void gload_lds16(const void* g, void* l) {
  auto gp = (const __attribute__((address_space(1))) unsigned int*)(uintptr_t)g;
  auto lp = (__attribute__((address_space(3))) unsigned int*)(unsigned int)(uintptr_t)l;
  __builtin_amdgcn_global_load_lds(gp, lp, 16, 0, 0);
}

// ---------------- f32 -> bf16 convert (8 elems/thread) ----------------
__global__ void k_cvt(const float* __restrict__ in, unsigned short* __restrict__ out, int n8) {
  int i = blockIdx.x * blockDim.x + threadIdx.x;
  if (i >= n8) return;
  const float4* p = (const float4*)in + (size_t)i * 2;
  float4 a = p[0], b = p[1];
  u16x8 o;
  o[0] = f2bf(a.x); o[1] = f2bf(a.y); o[2] = f2bf(a.z); o[3] = f2bf(a.w);
  o[4] = f2bf(b.x); o[5] = f2bf(b.y); o[6] = f2bf(b.z); o[7] = f2bf(b.w);
  *((u16x8*)out + i) = o;
}

// ---------------- GEMM C = A @ W^T (A:[M,K] bf16, W:[N,K] bf16) ----------------
// 128x128 tile, BK=32, 4 waves (2x2), 16x16x32 MFMA, 4x4 frags/wave.
template <int MODE>  // 0: bf16 out, 1: f32 out + bias
static __device__ __forceinline__ void gemm_body(
    const unsigned short* __restrict__ A, const unsigned short* __restrict__ W,
    unsigned short* __restrict__ Cb, float* __restrict__ Cf,
    const float* __restrict__ bias, int by, int bx,
    unsigned short* As, unsigned short* Bs) {
  const int K = KDIM, N = KDIM;
  int tid = threadIdx.x, lane = tid & 63, wid = tid >> 6;
  int r = lane & 15, g = lane >> 4;
  int wm = wid >> 1, wn = wid & 1;

  f32x4 acc[4][4];
#pragma unroll
  for (int m = 0; m < 4; ++m)
#pragma unroll
    for (int n = 0; n < 4; ++n) acc[m][n] = (f32x4){0.f, 0.f, 0.f, 0.f};

  const unsigned short* Ag = A + (size_t)(by * 128) * K;
  const unsigned short* Wg = W + (size_t)(bx * 128) * K;

  for (int k0 = 0; k0 < K; k0 += 32) {
#pragma unroll
    for (int it = 0; it < 2; ++it) {
      int base = it * 256 + wid * 64;  // wave-uniform chunk base
      int c = base + lane;             // chunk 0..511; row=c>>2, colchunk=c&3
      gload_lds16(Ag + (size_t)(c >> 2) * K + k0 + (c & 3) * 8, &As[base * 8]);
      gload_lds16(Wg + (size_t)(c >> 2) * K + k0 + (c & 3) * 8, &Bs[base * 8]);
    }
    __syncthreads();
    bf16x8 af[4], bf[4];
#pragma unroll
    for (int m = 0; m < 4; ++m) af[m] = ld_frag(&As[(wm * 64 + m * 16 + r) * 32 + g * 8]);
#pragma unroll
    for (int n = 0; n < 4; ++n) bf[n] = ld_frag(&Bs[(wn * 64 + n * 16 + r) * 32 + g * 8]);
#pragma unroll
    for (int m = 0; m < 4; ++m)
#pragma unroll
      for (int n = 0; n < 4; ++n)
        acc[m][n] = __builtin_amdgcn_mfma_f32_16x16x32_bf16(af[m], bf[n], acc[m][n], 0, 0, 0);
    __syncthreads();
  }

#pragma unroll
  for (int m = 0; m < 4; ++m)
#pragma unroll
    for (int n = 0; n < 4; ++n) {
      int col = bx * 128 + wn * 64 + n * 16 + r;
#pragma unroll
      for (int j = 0; j < 4; ++j) {
        int row = by * 128 + wm * 64 + m * 16 + g * 4 + j;
        if (MODE == 0)
          Cb[(size_t)row * N + col] = f2bf(acc[m][n][j]);
        else
          Cf[(size_t)row * N + col] = acc[m][n][j] + bias[col];
      }
    }
}

__global__ __launch_bounds__(256) void k_gemm_qkv(
    const unsigned short* __restrict__ X,
    const unsigned short* __restrict__ Wq, const unsigned short* __restrict__ Wk,
    const unsigned short* __restrict__ Wv,
    unsigned short* __restrict__ Q, unsigned short* __restrict__ Kp,
    unsigned short* __restrict__ V) {
  __shared__ __align__(16) unsigned short As[4096];
  __shared__ __align__(16) unsigned short Bs[4096];
  int idx = blockIdx.x;            // 32 * 24
  int by = idx / 24, bxx = idx % 24;
  int which = bxx >> 3, bx = bxx & 7;
  const unsigned short* W = (which == 0) ? Wq : (which == 1) ? Wk : Wv;
  unsigned short* C = (which == 0) ? Q : (which == 1) ? Kp : V;
  gemm_body<0>(X, W, C, nullptr, nullptr, by, bx, As, Bs);
}

__global__ __launch_bounds__(256) void k_gemm_out(
    const unsigned short* __restrict__ AO, const unsigned short* __restrict__ Wo,
    float* __restrict__ out, const float* __restrict__ bias) {
  __shared__ __align__(16) unsigned short As[4096];
  __shared__ __align__(16) unsigned short Bs[4096];
  int by = blockIdx.x >> 3, bx = blockIdx.x & 7;
  gemm_body<1>(AO, Wo, nullptr, out, bias, by, bx, As, Bs);
}

// ---------------- V [b,t,h*64+d] -> Vt [b,h,d,t] ----------------
__global__ __launch_bounds__(256) void k_transpose_v(
    const unsigned short* __restrict__ V, unsigned short* __restrict__ Vt) {
  int tt = blockIdx.x & 31, bh = blockIdx.x >> 5;
  int b = bh >> 4, h = bh & 15;
  __shared__ __align__(16) unsigned short ls[64][72];
  int tid = threadIdx.x;
#pragma unroll
  for (int it = 0; it < 2; ++it) {
    int c = it * 256 + tid;
    int t = c >> 3, d0 = (c & 7) * 8;
    const unsigned short* src = V + ((size_t)(b * TB + tt * 64 + t)) * KDIM + h * HD + d0;
    *(u16x8*)&ls[t][d0] = *(const u16x8*)src;
  }
  __syncthreads();
#pragma unroll
  for (int it = 0; it < 2; ++it) {
    int c = it * 256 + tid;
    int d = c >> 3, t0 = (c & 7) * 8;
    u16x8 v;
#pragma unroll
    for (int j = 0; j < 8; ++j) v[j] = ls[t0 + j][d];
    unsigned short* dst = Vt + ((size_t)(bh * HD + d)) * TB + tt * 64 + t0;
    *(u16x8*)dst = v;
  }
}

// ---------------- flash attention (swapped QK^T, 32x32x16 MFMA) ----------------
// grid: b*h*(T/128) blocks, 256 threads (4 waves). Wave w owns 32 Q rows.
// S^T = K_tile @ Q^T: each lane holds 32 of 64 scores for query q=lane&31
// (partner lane^32 holds the rest). Softmax in-register + shfl_xor(32).
// P round-trips through a per-wave swizzled LDS buffer so the MFMA operand
// k-mapping cancels between A(P) and B(V).
__global__ __launch_bounds__(256) void k_attn(
    const unsigned short* __restrict__ Q, const unsigned short* __restrict__ Kp,
    const unsigned short* __restrict__ Vt, unsigned short* __restrict__ AO) {
  __shared__ __align__(16) unsigned short Ks[64 * 64];   // [key][d], swizzled 16B blocks
  __shared__ __align__(16) unsigned short Vs[64 * 64];   // [d][key], swizzled
  __shared__ __align__(16) unsigned short Pb[4][32 * 64]; // per-wave P [q][k], swizzled

  int qt = blockIdx.x & 15, bh = blockIdx.x >> 4;
  int b = bh >> 4, h = bh & 15;
  int tid = threadIdx.x, lane = tid & 63, w = tid >> 6;
  int q = lane & 31, hh = lane >> 5;
  const float LOG2E = 1.44269504f;

  // Q fragments (B operand): lane holds Q[qrow = q][16f + 8*hh + j]
  const unsigned short* Qp =
      Q + ((size_t)(b * TB + qt * 128 + w * 32 + q)) * KDIM + h * HD;
  bf16x8 qf[4];
#pragma unroll
  for (int f = 0; f < 4; ++f) qf[f] = ld_frag(&Qp[16 * f + 8 * hh]);

  f32x16 o0, o1;  // O cols d=0..31 / 32..63; rows = C/D reg mapping
#pragma unroll
  for (int i = 0; i < 16; ++i) { o0[i] = 0.f; o1[i] = 0.f; }
  float m_run = -1e30f, l_run = 0.f;

  const unsigned short* Kbase = Kp + (size_t)(b * TB) * KDIM + h * HD;
  const unsigned short* Vbase = Vt + (size_t)bh * HD * TB;
  unsigned short* Pw = &Pb[w][0];

  for (int kt = 0; kt < TB / 64; ++kt) {
    // stage K[64 keys][64 d] and Vt[64 d][64 keys], content swizzled via
    // pre-swizzled global source (LDS[r][bl] = G[r][bl ^ (r&7)], 16B blocks)
#pragma unroll
    for (int it = 0; it < 2; ++it) {
      int base = it * 256 + w * 64;
      int c = base + lane;            // 0..511
      int rr = c >> 3;
      int blk = (c & 7) ^ (rr & 7);
      gload_lds16(Kbase + (size_t)(kt * 64 + rr) * KDIM + blk * 8, &Ks[base * 8]);
      gload_lds16(Vbase + (size_t)rr * TB + kt * 64 + blk * 8, &Vs[base * 8]);
    }
    __syncthreads();

    // S^T = K_tile @ Q^T, two 32-key groups. Lane: col q, rows = keys.
    f32x16 st[2];
#pragma unroll
    for (int g = 0; g < 2; ++g) {
#pragma unroll
      for (int i = 0; i < 16; ++i) st[g][i] = 0.f;
#pragma unroll
      for (int f = 0; f < 4; ++f) {
        int row = g * 32 + q;
        int bl = (2 * f + hh) ^ (row & 7);
        bf16x8 kf = ld_frag(&Ks[row * 64 + bl * 8]);
        st[g] = __builtin_amdgcn_mfma_f32_32x32x16_bf16(kf, qf[f], st[g], 0, 0, 0);
      }
    }

    // online softmax (scores scaled by 0.125 = 1/sqrt(64), folded into exp2)
    float pm = -1e30f;
#pragma unroll
    for (int g = 0; g < 2; ++g)
#pragma unroll
      for (int i = 0; i < 16; ++i) pm = fmaxf(pm, st[g][i]);
    pm = fmaxf(pm, __shfl_xor(pm, 32));
    float spm = pm * 0.125f;
    if (!__all(spm <= m_run + 8.f)) {   // defer-max (T13)
      float mnew = fmaxf(m_run, spm);
      float sc = __expf(m_run - mnew);
      m_run = mnew;
      l_run *= sc;
#pragma unroll
      for (int p = 0; p < 16; ++p) {
        float scp = __shfl(sc, (p & 3) + 8 * (p >> 2) + 4 * hh);
        o0[p] *= scp;
        o1[p] *= scp;
      }
    }
    float c1 = 0.125f * LOG2E, c2 = m_run * LOG2E;
    float rs = 0.f;
    unsigned pw[16];
#pragma unroll
    for (int g = 0; g < 2; ++g)
#pragma unroll
      for (int i = 0; i < 8; ++i) {
        float pa = exp2f(st[g][2 * i]     * c1 - c2);
        float pb = exp2f(st[g][2 * i + 1] * c1 - c2);
        rs += pa + pb;
        pw[g * 8 + i] = pack_bf(pa, pb);
      }
    rs += __shfl_xor(rs, 32);
    l_run += rs;

    // P -> per-wave LDS [q][k] (bf16, swizzled 16B blocks). Word (g,i) packs
    // keys k0 = 32g + 8*(i>>1) + 4*hh + 2*(i&1) + {0,1}.
#pragma unroll
    for (int g = 0; g < 2; ++g)
#pragma unroll
      for (int i = 0; i < 8; ++i) {
        int blk = (4 * g + (i >> 1)) ^ (q & 7);
        *(unsigned*)((char*)Pw + q * 128 + blk * 16 + 8 * hh + 4 * (i & 1)) =
            pw[g * 8 + i];
      }

    // O += P @ V  (A = P rows q, B = Vt rows d)
#pragma unroll
    for (int f = 0; f < 4; ++f) {
      int bl = (2 * f + hh) ^ (q & 7);
      bf16x8 pa = ld_frag(&Pw[q * 64 + bl * 8]);
      bf16x8 v0 = ld_frag(&Vs[q * 64 + bl * 8]);              // d rows 0..31
      bf16x8 v1 = ld_frag(&Vs[(32 + q) * 64 + bl * 8]);       // d rows 32..63
      o0 = __builtin_amdgcn_mfma_f32_32x32x16_bf16(pa, v0, o0, 0, 0, 0);
      o1 = __builtin_amdgcn_mfma_f32_32x32x16_bf16(pa, v1, o1, 0, 0, 0);
    }
    __syncthreads();
  }

  // epilogue: normalize rows and store bf16
  float invl = 1.0f / l_run;  // for q = lane&31 (both halves hold it)
#pragma unroll
  for (int p = 0; p < 16; ++p) {
    int qr = (p & 3) + 8 * (p >> 2) + 4 * hh;
    float il = __shfl(invl, qr);
    int row = qt * 128 + w * 32 + qr;
    size_t base = ((size_t)(b * TB + row)) * KDIM + h * HD;
    AO[base + q]      = f2bf(o0[p] * il);
    AO[base + 32 + q] = f2bf(o1[p] * il);
  }
}

// ---------------- launch ----------------
extern "C" void kernel_launch(void* const* d_in, const int* in_sizes, int n_in,
                              void* d_out, int out_size, void* d_ws, size_t ws_size,
                              hipStream_t stream) {
  const float* x  = (const float*)d_in[0];
  const float* Wq = (const float*)d_in[1];
  const float* Wk = (const float*)d_in[2];
  const float* Wv = (const float*)d_in[3];
  const float* Wo = (const float*)d_in[4];
  const float* bo = (const float*)d_in[5];

  char* ws = (char*)d_ws;
  const size_t MB = 1 << 20;
  unsigned short* xb  = (unsigned short*)(ws + 0 * MB);   // 8 MiB
  unsigned short* wqb = (unsigned short*)(ws + 8 * MB);   // 2 MiB
  unsigned short* wkb = (unsigned short*)(ws + 10 * MB);
  unsigned short* wvb = (unsigned short*)(ws + 12 * MB);
  unsigned short* wob = (unsigned short*)(ws + 14 * MB);
  unsigned short* Qb  = (unsigned short*)(ws + 16 * MB);  // 8 MiB
  unsigned short* Kb  = (unsigned short*)(ws + 24 * MB);
  unsigned short* Vb  = (unsigned short*)(ws + 32 * MB);
  unsigned short* Vtb = (unsigned short*)(ws + 40 * MB);
  unsigned short* AOb = (unsigned short*)(ws + 48 * MB);  // ends at 56 MiB

  k_cvt<<<2048, 256, 0, stream>>>(x, xb, (2 * TB * KDIM) / 8);
  k_cvt<<<512, 256, 0, stream>>>(Wq, wqb, (KDIM * KDIM) / 8);
  k_cvt<<<512, 256, 0, stream>>>(Wk, wkb, (KDIM * KDIM) / 8);
  k_cvt<<<512, 256, 0, stream>>>(Wv, wvb, (KDIM * KDIM) / 8);
  k_cvt<<<512, 256, 0, stream>>>(Wo, wob, (KDIM * KDIM) / 8);

  k_gemm_qkv<<<32 * 24, 256, 0, stream>>>(xb, wqb, wkb, wvb, Qb, Kb, Vb);
  k_transpose_v<<<1024, 256, 0, stream>>>(Vb, Vtb);
  k_attn<<<512, 256, 0, stream>>>(Qb, Kb, Vtb, AOb);
  k_gemm_out<<<256, 256, 0, stream>>>(AOb, wob, (float*)d_out, bo);
}

// Round 3
// 127.329 us; speedup vs baseline: 1.5043x; 1.2571x over previous
//
#include <hip/hip_runtime.h>
#include <stdint.h>
#include <stddef.h>

#define TB 2048
#define KDIM 1024
#define NH 16
#define HD 64

typedef __attribute__((ext_vector_type(8))) __bf16 bf16x8;
typedef __attribute__((ext_vector_type(4))) float f32x4;
typedef __attribute__((ext_vector_type(16))) float f32x16;
typedef __attribute__((ext_vector_type(8))) unsigned short u16x8;
typedef __attribute__((ext_vector_type(4))) unsigned u32x4;
typedef __attribute__((ext_vector_type(2))) unsigned u32x2;

static __device__ __forceinline__ unsigned short f2bf(float f) {
  unsigned u = __builtin_bit_cast(unsigned, f);
  return (unsigned short)((u + 0x7FFFu + ((u >> 16) & 1u)) >> 16);
}

static __device__ __forceinline__ bf16x8 ld_frag(const unsigned short* p) {
  u16x8 v = *(const u16x8*)p;
  return __builtin_bit_cast(bf16x8, v);
}

// global(16B per lane) -> LDS, linear lane order. LDS ptr must be wave-uniform.
static __device__ __forceinline__ void gload_lds16(const void* g, void* l) {
  auto gp = (const __attribute__((address_space(1))) unsigned int*)(uintptr_t)g;
  auto lp = (__attribute__((address_space(3))) unsigned int*)(unsigned int)(uintptr_t)l;
  __builtin_amdgcn_global_load_lds(gp, lp, 16, 0, 0);
}

static __device__ __forceinline__ float fast_exp2(float x) {
  float r;
  asm("v_exp_f32 %0, %1" : "=v"(r) : "v"(x));
  return r;
}

// dst = {bf16(a) lo, bf16(b) hi}
static __device__ __forceinline__ unsigned cvt_pk(float a, float b) {
  unsigned r;
  asm("v_cvt_pk_bf16_f32 %0, %1, %2" : "=v"(r) : "v"(a), "v"(b));
  return r;
}

// pair-register lane32 swap: ret.x = [a_lo | b_lo], ret.y = [a_hi | b_hi]
static __device__ __forceinline__ u32x2 permswap(unsigned a, unsigned b) {
  return __builtin_amdgcn_permlane32_swap(a, b, false, false);
}

// ---------------- fused f32 -> bf16 convert (8 elems/thread) ----------------
// blocks 0..2047: x (4M elems). blocks 2048..4095: W[q,k,v,o] (1M elems each,
// dsts contiguous at wb + wsel*1M).
__global__ __launch_bounds__(256) void k_cvt_all(
    const float* __restrict__ x, const float* __restrict__ Wq,
    const float* __restrict__ Wk, const float* __restrict__ Wv,
    const float* __restrict__ Wo, unsigned short* __restrict__ xb,
    unsigned short* __restrict__ wb) {
  int bb = blockIdx.x;
  const float* src;
  unsigned short* dst;
  int i;
  if (bb < 2048) {
    src = x; dst = xb; i = bb * 256 + threadIdx.x;
  } else {
    int wsel = (bb - 2048) >> 9;
    src = (wsel == 0) ? Wq : (wsel == 1) ? Wk : (wsel == 2) ? Wv : Wo;
    dst = wb + (size_t)wsel * (KDIM * KDIM);
    i = ((bb - 2048) & 511) * 256 + threadIdx.x;
  }
  const float4* p = (const float4*)src + (size_t)i * 2;
  float4 a = p[0], b = p[1];
  u16x8 o;
  o[0] = f2bf(a.x); o[1] = f2bf(a.y); o[2] = f2bf(a.z); o[3] = f2bf(a.w);
  o[4] = f2bf(b.x); o[5] = f2bf(b.y); o[6] = f2bf(b.z); o[7] = f2bf(b.w);
  *((u16x8*)dst + i) = o;
}

// ---------------- GEMM C = A @ W^T (A:[M,K] bf16, W:[N,K] bf16) ----------------
// 128x128 tile, BK=32, 4 waves (2x2), 16x16x32 MFMA, 4x4 frags/wave.
template <int MODE>  // 0: bf16 out, 1: f32 out + bias
static __device__ __forceinline__ void gemm_body(
    const unsigned short* __restrict__ A, const unsigned short* __restrict__ W,
    unsigned short* __restrict__ Cb, float* __restrict__ Cf,
    const float* __restrict__ bias, int by, int bx,
    unsigned short* As, unsigned short* Bs) {
  const int K = KDIM, N = KDIM;
  int tid = threadIdx.x, lane = tid & 63, wid = tid >> 6;
  int r = lane & 15, g = lane >> 4;
  int wm = wid >> 1, wn = wid & 1;

  f32x4 acc[4][4];
#pragma unroll
  for (int m = 0; m < 4; ++m)
#pragma unroll
    for (int n = 0; n < 4; ++n) acc[m][n] = (f32x4){0.f, 0.f, 0.f, 0.f};

  const unsigned short* Ag = A + (size_t)(by * 128) * K;
  const unsigned short* Wg = W + (size_t)(bx * 128) * K;

  for (int k0 = 0; k0 < K; k0 += 32) {
#pragma unroll
    for (int it = 0; it < 2; ++it) {
      int base = it * 256 + wid * 64;  // wave-uniform chunk base
      int c = base + lane;             // chunk 0..511; row=c>>2, colchunk=c&3
      gload_lds16(Ag + (size_t)(c >> 2) * K + k0 + (c & 3) * 8, &As[base * 8]);
      gload_lds16(Wg + (size_t)(c >> 2) * K + k0 + (c & 3) * 8, &Bs[base * 8]);
    }
    __syncthreads();
    bf16x8 af[4], bf[4];
#pragma unroll
    for (int m = 0; m < 4; ++m) af[m] = ld_frag(&As[(wm * 64 + m * 16 + r) * 32 + g * 8]);
#pragma unroll
    for (int n = 0; n < 4; ++n) bf[n] = ld_frag(&Bs[(wn * 64 + n * 16 + r) * 32 + g * 8]);
#pragma unroll
    for (int m = 0; m < 4; ++m)
#pragma unroll
      for (int n = 0; n < 4; ++n)
        acc[m][n] = __builtin_amdgcn_mfma_f32_16x16x32_bf16(af[m], bf[n], acc[m][n], 0, 0, 0);
    __syncthreads();
  }

#pragma unroll
  for (int m = 0; m < 4; ++m)
#pragma unroll
    for (int n = 0; n < 4; ++n) {
      int col = bx * 128 + wn * 64 + n * 16 + r;
#pragma unroll
      for (int j = 0; j < 4; ++j) {
        int row = by * 128 + wm * 64 + m * 16 + g * 4 + j;
        if (MODE == 0)
          Cb[(size_t)row * N + col] = f2bf(acc[m][n][j]);
        else
          Cf[(size_t)row * N + col] = acc[m][n][j] + bias[col];
      }
    }
}

__global__ __launch_bounds__(256) void k_gemm_qkv(
    const unsigned short* __restrict__ X,
    const unsigned short* __restrict__ Wq, const unsigned short* __restrict__ Wk,
    const unsigned short* __restrict__ Wv,
    unsigned short* __restrict__ Q, unsigned short* __restrict__ Kp,
    unsigned short* __restrict__ V) {
  __shared__ __align__(16) unsigned short As[4096];
  __shared__ __align__(16) unsigned short Bs[4096];
  int idx = blockIdx.x;            // 32 * 24
  int by = idx / 24, bxx = idx % 24;
  int which = bxx >> 3, bx = bxx & 7;
  const unsigned short* W = (which == 0) ? Wq : (which == 1) ? Wk : Wv;
  unsigned short* C = (which == 0) ? Q : (which == 1) ? Kp : V;
  gemm_body<0>(X, W, C, nullptr, nullptr, by, bx, As, Bs);
}

__global__ __launch_bounds__(256) void k_gemm_out(
    const unsigned short* __restrict__ AO, const unsigned short* __restrict__ Wo,
    float* __restrict__ out, const float* __restrict__ bias) {
  __shared__ __align__(16) unsigned short As[4096];
  __shared__ __align__(16) unsigned short Bs[4096];
  int by = blockIdx.x >> 3, bx = blockIdx.x & 7;
  gemm_body<1>(AO, Wo, nullptr, out, bias, by, bx, As, Bs);
}

// ---------------- V [b,t,h*64+d] -> Vt [b,h,d,t] ----------------
__global__ __launch_bounds__(256) void k_transpose_v(
    const unsigned short* __restrict__ V, unsigned short* __restrict__ Vt) {
  int tt = blockIdx.x & 31, bh = blockIdx.x >> 5;
  int b = bh >> 4, h = bh & 15;
  __shared__ __align__(16) unsigned short ls[64][72];
  int tid = threadIdx.x;
#pragma unroll
  for (int it = 0; it < 2; ++it) {
    int c = it * 256 + tid;
    int t = c >> 3, d0 = (c & 7) * 8;
    const unsigned short* src = V + ((size_t)(b * TB + tt * 64 + t)) * KDIM + h * HD + d0;
    *(u16x8*)&ls[t][d0] = *(const u16x8*)src;
  }
  __syncthreads();
#pragma unroll
  for (int it = 0; it < 2; ++it) {
    int c = it * 256 + tid;
    int d = c >> 3, t0 = (c & 7) * 8;
    u16x8 v;
#pragma unroll
    for (int j = 0; j < 8; ++j) v[j] = ls[t0 + j][d];
    unsigned short* dst = Vt + ((size_t)(bh * HD + d)) * TB + tt * 64 + t0;
    *(u16x8*)dst = v;
  }
}

// ---------------- flash attention (swapped QK^T, 32x32x16 MFMA, T12) -----------
// grid: b*h*(T/128) blocks, 256 threads (4 waves). Wave w owns 32 Q rows.
// S^T = K_tile @ Q^T: lane (q,hh) holds 32 of 64 scores for query row q at keys
// k=(i&3)+8*(i>>2)+4*hh+32g. Softmax in-register; P packed to bf16 via
// v_cvt_pk_bf16_f32 and redistributed with permlane32_swap so each lane holds
// the PV A-fragments (k = 16s + 8*hh + j) directly — no LDS round-trip.
// K/V tiles double-buffered in LDS (one barrier per tile).
__global__ __launch_bounds__(256) void k_attn(
    const unsigned short* __restrict__ Q, const unsigned short* __restrict__ Kp,
    const unsigned short* __restrict__ Vt, unsigned short* __restrict__ AO) {
  __shared__ __align__(16) unsigned short Ks[2][64 * 64];  // [key][d], swizzled 16B blocks
  __shared__ __align__(16) unsigned short Vs[2][64 * 64];  // [d][key], swizzled

  int qt = blockIdx.x & 15, bh = blockIdx.x >> 4;
  int b = bh >> 4, h = bh & 15;
  int tid = threadIdx.x, lane = tid & 63, w = tid >> 6;
  int q = lane & 31, hh = lane >> 5;
  const float LOG2E = 1.44269504f;
  const int NT = TB / 64;

  // Q fragments (B operand): lane holds Q[row q][16f + 8*hh + j]
  const unsigned short* Qp =
      Q + ((size_t)(b * TB + qt * 128 + w * 32 + q)) * KDIM + h * HD;
  bf16x8 qf[4];
#pragma unroll
  for (int f = 0; f < 4; ++f) qf[f] = ld_frag(&Qp[16 * f + 8 * hh]);

  f32x16 o0, o1;  // O cols d=0..31 / 32..63; rows = C/D reg mapping
#pragma unroll
  for (int i = 0; i < 16; ++i) { o0[i] = 0.f; o1[i] = 0.f; }
  float m_run = -1e30f, l_run = 0.f;

  const unsigned short* Kbase = Kp + (size_t)(b * TB) * KDIM + h * HD;
  const unsigned short* Vbase = Vt + (size_t)bh * HD * TB;

  auto stage = [&](int kt, int buf) {
#pragma unroll
    for (int it = 0; it < 2; ++it) {
      int base = it * 256 + w * 64;
      int c = base + lane;            // 0..511
      int rr = c >> 3;
      int blk = (c & 7) ^ (rr & 7);   // pre-swizzled global source
      gload_lds16(Kbase + (size_t)(kt * 64 + rr) * KDIM + blk * 8, &Ks[buf][base * 8]);
      gload_lds16(Vbase + (size_t)rr * TB + kt * 64 + blk * 8, &Vs[buf][base * 8]);
    }
  };

  stage(0, 0);
  __syncthreads();
  int cur = 0;

  for (int kt = 0; kt < NT; ++kt) {
    if (kt + 1 < NT) stage(kt + 1, cur ^ 1);

    // S^T = K_tile @ Q^T, two 32-key groups. Lane: col q, rows = keys.
    const unsigned short* Kc = &Ks[cur][0];
    f32x16 st[2];
    __builtin_amdgcn_s_setprio(1);
#pragma unroll
    for (int g = 0; g < 2; ++g) {
#pragma unroll
      for (int i = 0; i < 16; ++i) st[g][i] = 0.f;
#pragma unroll
      for (int f = 0; f < 4; ++f) {
        int row = g * 32 + q;
        int bl = (2 * f + hh) ^ (row & 7);
        bf16x8 kf = ld_frag(&Kc[row * 64 + bl * 8]);
        st[g] = __builtin_amdgcn_mfma_f32_32x32x16_bf16(kf, qf[f], st[g], 0, 0, 0);
      }
    }
    __builtin_amdgcn_s_setprio(0);

    // online softmax (scale 0.125 = 1/sqrt(64) folded into exp2)
    float pm = -1e30f;
#pragma unroll
    for (int g = 0; g < 2; ++g)
#pragma unroll
      for (int i = 0; i < 16; ++i) pm = fmaxf(pm, st[g][i]);
    pm = fmaxf(pm, __shfl_xor(pm, 32));
    float spm = pm * 0.125f;
    if (!__all(spm <= m_run + 8.f)) {   // defer-max (T13)
      float mnew = fmaxf(m_run, spm);
      float sc = fast_exp2((m_run - mnew) * LOG2E);
      m_run = mnew;
      l_run *= sc;
#pragma unroll
      for (int p = 0; p < 16; ++p) {
        float scp = __shfl(sc, (p & 3) + 8 * (p >> 2) + 4 * hh);
        o0[p] *= scp;
        o1[p] *= scp;
      }
    }

    // P = exp(S - m), packed to bf16 fragments in-register (T12).
    float c1 = 0.125f * LOG2E, c2 = m_run * LOG2E;
    float rs = 0.f;
    bf16x8 pa[4];
#pragma unroll
    for (int g = 0; g < 2; ++g) {
      float e[16];
#pragma unroll
      for (int i = 0; i < 16; ++i) {
        e[i] = fast_exp2(st[g][i] * c1 - c2);
        rs += e[i];
      }
      unsigned d[8];
#pragma unroll
      for (int i = 0; i < 8; ++i) d[i] = cvt_pk(e[2 * i], e[2 * i + 1]);
      u32x2 r1 = permswap(d[0], d[2]);
      u32x2 r2 = permswap(d[1], d[3]);
      u32x2 r3 = permswap(d[4], d[6]);
      u32x2 r4 = permswap(d[5], d[7]);
      u32x4 t0; t0[0] = r1.x; t0[1] = r2.x; t0[2] = r1.y; t0[3] = r2.y;
      u32x4 t1; t1[0] = r3.x; t1[1] = r4.x; t1[2] = r3.y; t1[3] = r4.y;
      pa[2 * g]     = __builtin_bit_cast(bf16x8, t0);
      pa[2 * g + 1] = __builtin_bit_cast(bf16x8, t1);
    }
    rs += __shfl_xor(rs, 32);
    l_run += rs;

    // O += P @ V  (A = pa fragments, B = Vt rows d)
    const unsigned short* Vc = &Vs[cur][0];
    __builtin_amdgcn_s_setprio(1);
#pragma unroll
    for (int s = 0; s < 4; ++s) {
      int bl = (2 * s + hh) ^ (q & 7);
      bf16x8 v0 = ld_frag(&Vc[q * 64 + bl * 8]);          // d rows 0..31
      bf16x8 v1 = ld_frag(&Vc[(32 + q) * 64 + bl * 8]);   // d rows 32..63
      o0 = __builtin_amdgcn_mfma_f32_32x32x16_bf16(pa[s], v0, o0, 0, 0, 0);
      o1 = __builtin_amdgcn_mfma_f32_32x32x16_bf16(pa[s], v1, o1, 0, 0, 0);
    }
    __builtin_amdgcn_s_setprio(0);

    __syncthreads();   // staged kt+1 visible; buf[cur] reads done
    cur ^= 1;
  }

  // epilogue: normalize rows and store bf16
  float invl = 1.0f / l_run;  // for q-row = lane&31 (both halves hold it)
#pragma unroll
  for (int p = 0; p < 16; ++p) {
    int qr = (p & 3) + 8 * (p >> 2) + 4 * hh;
    float il = __shfl(invl, qr);
    int row = qt * 128 + w * 32 + qr;
    size_t base = ((size_t)(b * TB + row)) * KDIM + h * HD;
    AO[base + q]      = f2bf(o0[p] * il);
    AO[base + 32 + q] = f2bf(o1[p] * il);
  }
}

// ---------------- launch ----------------
extern "C" void kernel_launch(void* const* d_in, const int* in_sizes, int n_in,
                              void* d_out, int out_size, void* d_ws, size_t ws_size,
                              hipStream_t stream) {
  const float* x  = (const float*)d_in[0];
  const float* Wq = (const float*)d_in[1];
  const float* Wk = (const float*)d_in[2];
  const float* Wv = (const float*)d_in[3];
  const float* Wo = (const float*)d_in[4];
  const float* bo = (const float*)d_in[5];

  char* ws = (char*)d_ws;
  const size_t MB = 1 << 20;
  unsigned short* xb  = (unsigned short*)(ws + 0 * MB);   // 8 MiB
  unsigned short* wqb = (unsigned short*)(ws + 8 * MB);   // 4 x 2 MiB contiguous
  unsigned short* wkb = (unsigned short*)(ws + 10 * MB);
  unsigned short* wvb = (unsigned short*)(ws + 12 * MB);
  unsigned short* wob = (unsigned short*)(ws + 14 * MB);
  unsigned short* Qb  = (unsigned short*)(ws + 16 * MB);  // 8 MiB
  unsigned short* Kb  = (unsigned short*)(ws + 24 * MB);
  unsigned short* Vb  = (unsigned short*)(ws + 32 * MB);
  unsigned short* Vtb = (unsigned short*)(ws + 40 * MB);
  unsigned short* AOb = (unsigned short*)(ws + 48 * MB);  // ends at 56 MiB

  k_cvt_all<<<4096, 256, 0, stream>>>(x, Wq, Wk, Wv, Wo, xb, wqb);
  k_gemm_qkv<<<32 * 24, 256, 0, stream>>>(xb, wqb, wkb, wvb, Qb, Kb, Vb);
  k_transpose_v<<<1024, 256, 0, stream>>>(Vb, Vtb);
  k_attn<<<512, 256, 0, stream>>>(Qb, Kb, Vtb, AOb);
  k_gemm_out<<<256, 256, 0, stream>>>(AOb, wob, (float*)d_out, bo);
}

// Round 4
// 125.477 us; speedup vs baseline: 1.5265x; 1.0148x over previous
//
#include <hip/hip_runtime.h>
#include <stdint.h>
#include <stddef.h>

#define TB 2048
#define KDIM 1024
#define NH 16
#define HD 64

typedef __attribute__((ext_vector_type(8))) __bf16 bf16x8;
typedef __attribute__((ext_vector_type(4))) float f32x4;
typedef __attribute__((ext_vector_type(16))) float f32x16;
typedef __attribute__((ext_vector_type(8))) unsigned short u16x8;
typedef __attribute__((ext_vector_type(4))) unsigned u32x4;
typedef __attribute__((ext_vector_type(2))) unsigned u32x2;

static __device__ __forceinline__ unsigned short f2bf(float f) {
  unsigned u = __builtin_bit_cast(unsigned, f);
  return (unsigned short)((u + 0x7FFFu + ((u >> 16) & 1u)) >> 16);
}

static __device__ __forceinline__ bf16x8 ld_frag(const unsigned short* p) {
  u16x8 v = *(const u16x8*)p;
  return __builtin_bit_cast(bf16x8, v);
}

// global(16B per lane) -> LDS, linear lane order. LDS ptr must be wave-uniform.
static __device__ __forceinline__ void gload_lds16(const void* g, void* l) {
  auto gp = (const __attribute__((address_space(1))) unsigned int*)(uintptr_t)g;
  auto lp = (__attribute__((address_space(3))) unsigned int*)(unsigned int)(uintptr_t)l;
  __builtin_amdgcn_global_load_lds(gp, lp, 16, 0, 0);
}

static __device__ __forceinline__ float fast_exp2(float x) {
  float r;
  asm("v_exp_f32 %0, %1" : "=v"(r) : "v"(x));
  return r;
}

// dst = {bf16(a) lo, bf16(b) hi}
static __device__ __forceinline__ unsigned cvt_pk(float a, float b) {
  unsigned r;
  asm("v_cvt_pk_bf16_f32 %0, %1, %2" : "=v"(r) : "v"(a), "v"(b));
  return r;
}

// pair-register lane32 swap: ret.x = [a_lo | b_lo], ret.y = [a_hi | b_hi]
static __device__ __forceinline__ u32x2 permswap(unsigned a, unsigned b) {
  return __builtin_amdgcn_permlane32_swap(a, b, false, false);
}

// ---------------- fused f32 -> bf16 convert (8 elems/thread) ----------------
__global__ __launch_bounds__(256) void k_cvt_all(
    const float* __restrict__ x, const float* __restrict__ Wq,
    const float* __restrict__ Wk, const float* __restrict__ Wv,
    const float* __restrict__ Wo, unsigned short* __restrict__ xb,
    unsigned short* __restrict__ wb) {
  int bb = blockIdx.x;
  const float* src;
  unsigned short* dst;
  int i;
  if (bb < 2048) {
    src = x; dst = xb; i = bb * 256 + threadIdx.x;
  } else {
    int wsel = (bb - 2048) >> 9;
    src = (wsel == 0) ? Wq : (wsel == 1) ? Wk : (wsel == 2) ? Wv : Wo;
    dst = wb + (size_t)wsel * (KDIM * KDIM);
    i = ((bb - 2048) & 511) * 256 + threadIdx.x;
  }
  const float4* p = (const float4*)src + (size_t)i * 2;
  float4 a = p[0], b = p[1];
  u16x8 o;
  o[0] = f2bf(a.x); o[1] = f2bf(a.y); o[2] = f2bf(a.z); o[3] = f2bf(a.w);
  o[4] = f2bf(b.x); o[5] = f2bf(b.y); o[6] = f2bf(b.z); o[7] = f2bf(b.w);
  *((u16x8*)dst + i) = o;
}

// ---------------- GEMM C = A @ W^T (A:[M,K] bf16, W:[N,K] bf16) ----------------
template <int MODE>  // 0: bf16 out, 1: f32 out + bias
static __device__ __forceinline__ void gemm_body(
    const unsigned short* __restrict__ A, const unsigned short* __restrict__ W,
    unsigned short* __restrict__ Cb, float* __restrict__ Cf,
    const float* __restrict__ bias, int by, int bx,
    unsigned short* As, unsigned short* Bs) {
  const int K = KDIM, N = KDIM;
  int tid = threadIdx.x, lane = tid & 63, wid = tid >> 6;
  int r = lane & 15, g = lane >> 4;
  int wm = wid >> 1, wn = wid & 1;

  f32x4 acc[4][4];
#pragma unroll
  for (int m = 0; m < 4; ++m)
#pragma unroll
    for (int n = 0; n < 4; ++n) acc[m][n] = (f32x4){0.f, 0.f, 0.f, 0.f};

  const unsigned short* Ag = A + (size_t)(by * 128) * K;
  const unsigned short* Wg = W + (size_t)(bx * 128) * K;

  for (int k0 = 0; k0 < K; k0 += 32) {
#pragma unroll
    for (int it = 0; it < 2; ++it) {
      int base = it * 256 + wid * 64;
      int c = base + lane;
      gload_lds16(Ag + (size_t)(c >> 2) * K + k0 + (c & 3) * 8, &As[base * 8]);
      gload_lds16(Wg + (size_t)(c >> 2) * K + k0 + (c & 3) * 8, &Bs[base * 8]);
    }
    __syncthreads();
    bf16x8 af[4], bf[4];
#pragma unroll
    for (int m = 0; m < 4; ++m) af[m] = ld_frag(&As[(wm * 64 + m * 16 + r) * 32 + g * 8]);
#pragma unroll
    for (int n = 0; n < 4; ++n) bf[n] = ld_frag(&Bs[(wn * 64 + n * 16 + r) * 32 + g * 8]);
#pragma unroll
    for (int m = 0; m < 4; ++m)
#pragma unroll
      for (int n = 0; n < 4; ++n)
        acc[m][n] = __builtin_amdgcn_mfma_f32_16x16x32_bf16(af[m], bf[n], acc[m][n], 0, 0, 0);
    __syncthreads();
  }

#pragma unroll
  for (int m = 0; m < 4; ++m)
#pragma unroll
    for (int n = 0; n < 4; ++n) {
      int col = bx * 128 + wn * 64 + n * 16 + r;
#pragma unroll
      for (int j = 0; j < 4; ++j) {
        int row = by * 128 + wm * 64 + m * 16 + g * 4 + j;
        if (MODE == 0)
          Cb[(size_t)row * N + col] = f2bf(acc[m][n][j]);
        else
          Cf[(size_t)row * N + col] = acc[m][n][j] + bias[col];
      }
    }
}

__global__ __launch_bounds__(256) void k_gemm_qkv(
    const unsigned short* __restrict__ X,
    const unsigned short* __restrict__ Wq, const unsigned short* __restrict__ Wk,
    const unsigned short* __restrict__ Wv,
    unsigned short* __restrict__ Q, unsigned short* __restrict__ Kp,
    unsigned short* __restrict__ V) {
  __shared__ __align__(16) unsigned short As[4096];
  __shared__ __align__(16) unsigned short Bs[4096];
  int idx = blockIdx.x;            // 32 * 24
  int by = idx / 24, bxx = idx % 24;
  int which = bxx >> 3, bx = bxx & 7;
  const unsigned short* W = (which == 0) ? Wq : (which == 1) ? Wk : Wv;
  unsigned short* C = (which == 0) ? Q : (which == 1) ? Kp : V;
  gemm_body<0>(X, W, C, nullptr, nullptr, by, bx, As, Bs);
}

__global__ __launch_bounds__(256) void k_gemm_out(
    const unsigned short* __restrict__ AO, const unsigned short* __restrict__ Wo,
    float* __restrict__ out, const float* __restrict__ bias) {
  __shared__ __align__(16) unsigned short As[4096];
  __shared__ __align__(16) unsigned short Bs[4096];
  int by = blockIdx.x >> 3, bx = blockIdx.x & 7;
  gemm_body<1>(AO, Wo, nullptr, out, bias, by, bx, As, Bs);
}

// ---------------- V [b,t,h*64+d] -> Vt [b,h,d,t] ----------------
__global__ __launch_bounds__(256) void k_transpose_v(
    const unsigned short* __restrict__ V, unsigned short* __restrict__ Vt) {
  int tt = blockIdx.x & 31, bh = blockIdx.x >> 5;
  int b = bh >> 4, h = bh & 15;
  __shared__ __align__(16) unsigned short ls[64][72];
  int tid = threadIdx.x;
#pragma unroll
  for (int it = 0; it < 2; ++it) {
    int c = it * 256 + tid;
    int t = c >> 3, d0 = (c & 7) * 8;
    const unsigned short* src = V + ((size_t)(b * TB + tt * 64 + t)) * KDIM + h * HD + d0;
    *(u16x8*)&ls[t][d0] = *(const u16x8*)src;
  }
  __syncthreads();
#pragma unroll
  for (int it = 0; it < 2; ++it) {
    int c = it * 256 + tid;
    int d = c >> 3, t0 = (c & 7) * 8;
    u16x8 v;
#pragma unroll
    for (int j = 0; j < 8; ++j) v[j] = ls[t0 + j][d];
    unsigned short* dst = Vt + ((size_t)(bh * HD + d)) * TB + tt * 64 + t0;
    *(u16x8*)dst = v;
  }
}

// ---------------- flash attention (swapped QK^T, 32x32x16, in-block KV split) --
// grid: b*h*(T/128) blocks, 512 threads (8 waves). Wave w: qgroup wl=w&3 (32
// q-rows), half = w>>2 (KV tiles half*16..half*16+15). Both halves run in
// lockstep on separate LDS tile streams; merged at the end via LDS.
__global__ __launch_bounds__(512, 4) void k_attn(
    const unsigned short* __restrict__ Q, const unsigned short* __restrict__ Kp,
    const unsigned short* __restrict__ Vt, unsigned short* __restrict__ AO) {
  __shared__ __align__(16) unsigned short Ks[2][2][4096];  // [half][buf][key][d]
  __shared__ __align__(16) unsigned short Vs[2][2][4096];  // [half][buf][d][key]

  int qt = blockIdx.x & 15, bh = blockIdx.x >> 4;
  int b = bh >> 4, h = bh & 15;
  int tid = threadIdx.x, lane = tid & 63, w = tid >> 6;
  int wl = w & 3, half = w >> 2;
  int q = lane & 31, hh = lane >> 5;
  const float LOG2E = 1.44269504f;
  const int HT = (TB / 64) / 2;  // 16 tiles per half

  const unsigned short* Qp =
      Q + ((size_t)(b * TB + qt * 128 + wl * 32 + q)) * KDIM + h * HD;
  bf16x8 qf[4];
#pragma unroll
  for (int f = 0; f < 4; ++f) qf[f] = ld_frag(&Qp[16 * f + 8 * hh]);

  f32x16 o0, o1;
#pragma unroll
  for (int i = 0; i < 16; ++i) { o0[i] = 0.f; o1[i] = 0.f; }
  float m_run = -1e30f, l_run = 0.f;

  const unsigned short* Kbase = Kp + (size_t)(b * TB) * KDIM + h * HD;
  const unsigned short* Vbase = Vt + (size_t)bh * HD * TB;

  auto stage = [&](int kt, int buf) {
#pragma unroll
    for (int it = 0; it < 2; ++it) {
      int base = it * 256 + wl * 64;
      int c = base + lane;
      int rr = c >> 3;
      int blk = (c & 7) ^ (rr & 7);   // pre-swizzled global source
      gload_lds16(Kbase + (size_t)(kt * 64 + rr) * KDIM + blk * 8,
                  &Ks[half][buf][base * 8]);
      gload_lds16(Vbase + (size_t)rr * TB + kt * 64 + blk * 8,
                  &Vs[half][buf][base * 8]);
    }
  };

  stage(half * HT, 0);
  __syncthreads();
  int cur = 0;

  for (int t = 0; t < HT; ++t) {
    if (t + 1 < HT) stage(half * HT + t + 1, cur ^ 1);

    // S^T = K_tile @ Q^T
    const unsigned short* Kc = &Ks[half][cur][0];
    f32x16 st[2];
    __builtin_amdgcn_s_setprio(1);
#pragma unroll
    for (int g = 0; g < 2; ++g) {
#pragma unroll
      for (int i = 0; i < 16; ++i) st[g][i] = 0.f;
#pragma unroll
      for (int f = 0; f < 4; ++f) {
        int row = g * 32 + q;
        int bl = (2 * f + hh) ^ (row & 7);
        bf16x8 kf = ld_frag(&Kc[row * 64 + bl * 8]);
        st[g] = __builtin_amdgcn_mfma_f32_32x32x16_bf16(kf, qf[f], st[g], 0, 0, 0);
      }
    }
    __builtin_amdgcn_s_setprio(0);

    // online softmax (4-way tree max; scale 0.125 folded into exp2)
    float pm4[4] = {-1e30f, -1e30f, -1e30f, -1e30f};
#pragma unroll
    for (int g = 0; g < 2; ++g)
#pragma unroll
      for (int i = 0; i < 16; ++i) pm4[i & 3] = fmaxf(pm4[i & 3], st[g][i]);
    float pm = fmaxf(fmaxf(pm4[0], pm4[1]), fmaxf(pm4[2], pm4[3]));
    pm = fmaxf(pm, __shfl_xor(pm, 32));
    float spm = pm * 0.125f;
    if (!__all(spm <= m_run + 8.f)) {   // defer-max (T13)
      float mnew = fmaxf(m_run, spm);
      float sc = fast_exp2((m_run - mnew) * LOG2E);
      m_run = mnew;
      l_run *= sc;
#pragma unroll
      for (int p = 0; p < 16; ++p) {
        float scp = __shfl(sc, (p & 3) + 8 * (p >> 2) + 4 * hh);
        o0[p] *= scp;
        o1[p] *= scp;
      }
    }

    // P = exp(S - m), packed to bf16 fragments in-register (T12)
    float c1 = 0.125f * LOG2E, c2 = m_run * LOG2E;
    float rs4[4] = {0.f, 0.f, 0.f, 0.f};
    bf16x8 pa[4];
#pragma unroll
    for (int g = 0; g < 2; ++g) {
      float e[16];
#pragma unroll
      for (int i = 0; i < 16; ++i) {
        e[i] = fast_exp2(st[g][i] * c1 - c2);
        rs4[i & 3] += e[i];
      }
      unsigned d[8];
#pragma unroll
      for (int i = 0; i < 8; ++i) d[i] = cvt_pk(e[2 * i], e[2 * i + 1]);
      u32x2 r1 = permswap(d[0], d[2]);
      u32x2 r2 = permswap(d[1], d[3]);
      u32x2 r3 = permswap(d[4], d[6]);
      u32x2 r4 = permswap(d[5], d[7]);
      u32x4 t0; t0[0] = r1.x; t0[1] = r2.x; t0[2] = r1.y; t0[3] = r2.y;
      u32x4 t1; t1[0] = r3.x; t1[1] = r4.x; t1[2] = r3.y; t1[3] = r4.y;
      pa[2 * g]     = __builtin_bit_cast(bf16x8, t0);
      pa[2 * g + 1] = __builtin_bit_cast(bf16x8, t1);
    }
    float rs = (rs4[0] + rs4[1]) + (rs4[2] + rs4[3]);
    rs += __shfl_xor(rs, 32);
    l_run += rs;

    // O += P @ V
    const unsigned short* Vc = &Vs[half][cur][0];
    __builtin_amdgcn_s_setprio(1);
#pragma unroll
    for (int s = 0; s < 4; ++s) {
      int bl = (2 * s + hh) ^ (q & 7);
      bf16x8 v0 = ld_frag(&Vc[q * 64 + bl * 8]);
      bf16x8 v1 = ld_frag(&Vc[(32 + q) * 64 + bl * 8]);
      o0 = __builtin_amdgcn_mfma_f32_32x32x16_bf16(pa[s], v0, o0, 0, 0, 0);
      o1 = __builtin_amdgcn_mfma_f32_32x32x16_bf16(pa[s], v1, o1, 0, 0, 0);
    }
    __builtin_amdgcn_s_setprio(0);

    __syncthreads();
    cur ^= 1;
  }

  // -------- merge halves via LDS (conflict-free [p][wl*64+lane] layout) --------
  float* Osw = (float*)&Vs[0][0][0];   // 32 KB = 32 x 256 floats
  float* MLb = (float*)&Ks[0][0][0];   // 256 floats
  if (half) {
#pragma unroll
    for (int p = 0; p < 16; ++p) {
      Osw[p * 256 + wl * 64 + lane]        = o0[p];
      Osw[(16 + p) * 256 + wl * 64 + lane] = o1[p];
    }
    if (!hh) {
      MLb[wl * 32 + q]       = m_run;
      MLb[128 + wl * 32 + q] = l_run;
    }
  }
  __syncthreads();
  if (!half) {
    float m2 = MLb[wl * 32 + q], l2 = MLb[128 + wl * 32 + q];
    float mm = fmaxf(m_run, m2);
    float ea = fast_exp2((m_run - mm) * LOG2E);
    float eb = fast_exp2((m2 - mm) * LOG2E);
    float il = 1.f / (l_run * ea + l2 * eb);
#pragma unroll
    for (int p = 0; p < 16; ++p) {
      int qr = (p & 3) + 8 * (p >> 2) + 4 * hh;
      float a  = __shfl(ea, qr);
      float bb = __shfl(eb, qr);
      float ip = __shfl(il, qr);
      float v0 = (o0[p] * a + Osw[p * 256 + wl * 64 + lane] * bb) * ip;
      float v1 = (o1[p] * a + Osw[(16 + p) * 256 + wl * 64 + lane] * bb) * ip;
      int row = qt * 128 + wl * 32 + qr;
      size_t base = ((size_t)(b * TB + row)) * KDIM + h * HD;
      AO[base + q]      = f2bf(v0);
      AO[base + 32 + q] = f2bf(v1);
    }
  }
}

// ---------------- launch ----------------
extern "C" void kernel_launch(void* const* d_in, const int* in_sizes, int n_in,
                              void* d_out, int out_size, void* d_ws, size_t ws_size,
                              hipStream_t stream) {
  const float* x  = (const float*)d_in[0];
  const float* Wq = (const float*)d_in[1];
  const float* Wk = (const float*)d_in[2];
  const float* Wv = (const float*)d_in[3];
  const float* Wo = (const float*)d_in[4];
  const float* bo = (const float*)d_in[5];

  char* ws = (char*)d_ws;
  const size_t MB = 1 << 20;
  unsigned short* xb  = (unsigned short*)(ws + 0 * MB);   // 8 MiB
  unsigned short* wqb = (unsigned short*)(ws + 8 * MB);   // 4 x 2 MiB contiguous
  unsigned short* wkb = (unsigned short*)(ws + 10 * MB);
  unsigned short* wvb = (unsigned short*)(ws + 12 * MB);
  unsigned short* wob = (unsigned short*)(ws + 14 * MB);
  unsigned short* Qb  = (unsigned short*)(ws + 16 * MB);  // 8 MiB
  unsigned short* Kb  = (unsigned short*)(ws + 24 * MB);
  unsigned short* Vb  = (unsigned short*)(ws + 32 * MB);
  unsigned short* Vtb = (unsigned short*)(ws + 40 * MB);
  unsigned short* AOb = (unsigned short*)(ws + 48 * MB);  // ends at 56 MiB

  k_cvt_all<<<4096, 256, 0, stream>>>(x, Wq, Wk, Wv, Wo, xb, wqb);
  k_gemm_qkv<<<32 * 24, 256, 0, stream>>>(xb, wqb, wkb, wvb, Qb, Kb, Vb);
  k_transpose_v<<<1024, 256, 0, stream>>>(Vb, Vtb);
  k_attn<<<512, 512, 0, stream>>>(Qb, Kb, Vtb, AOb);
  k_gemm_out<<<256, 256, 0, stream>>>(AOb, wob, (float*)d_out, bo);
}

// Round 5
// 120.207 us; speedup vs baseline: 1.5934x; 1.0438x over previous
//
#include <hip/hip_runtime.h>
#include <stdint.h>
#include <stddef.h>

#define TB 2048
#define KDIM 1024
#define NH 16
#define HD 64

typedef __attribute__((ext_vector_type(8))) __bf16 bf16x8;
typedef __attribute__((ext_vector_type(2))) float f32x2;
typedef __attribute__((ext_vector_type(4))) float f32x4;
typedef __attribute__((ext_vector_type(16))) float f32x16;
typedef __attribute__((ext_vector_type(4))) unsigned short u16x4;
typedef __attribute__((ext_vector_type(8))) unsigned short u16x8;
typedef __attribute__((ext_vector_type(4))) unsigned u32x4;
typedef __attribute__((ext_vector_type(2))) unsigned u32x2;

static __device__ __forceinline__ unsigned short f2bf(float f) {
  unsigned u = __builtin_bit_cast(unsigned, f);
  return (unsigned short)((u + 0x7FFFu + ((u >> 16) & 1u)) >> 16);
}

static __device__ __forceinline__ bf16x8 ld_frag(const unsigned short* p) {
  u16x8 v = *(const u16x8*)p;
  return __builtin_bit_cast(bf16x8, v);
}

// global(16B per lane) -> LDS, linear lane order. LDS ptr must be wave-uniform.
static __device__ __forceinline__ void gload_lds16(const void* g, void* l) {
  auto gp = (const __attribute__((address_space(1))) unsigned int*)(uintptr_t)g;
  auto lp = (__attribute__((address_space(3))) unsigned int*)(unsigned int)(uintptr_t)l;
  __builtin_amdgcn_global_load_lds(gp, lp, 16, 0, 0);
}

static __device__ __forceinline__ float fast_exp2(float x) {
  float r;
  asm("v_exp_f32 %0, %1" : "=v"(r) : "v"(x));
  return r;
}

static __device__ __forceinline__ unsigned cvt_pk(float a, float b) {
  unsigned r;
  asm("v_cvt_pk_bf16_f32 %0, %1, %2" : "=v"(r) : "v"(a), "v"(b));
  return r;
}

static __device__ __forceinline__ u32x2 permswap(unsigned a, unsigned b) {
  return __builtin_amdgcn_permlane32_swap(a, b, false, false);
}

// packed f32 math (VOP3P dual-issue) + 3-input max
static __device__ __forceinline__ f32x2 pk_fma(f32x2 a, f32x2 b, f32x2 c) {
  f32x2 d;
  asm("v_pk_fma_f32 %0, %1, %2, %3" : "=v"(d) : "v"(a), "v"(b), "v"(c));
  return d;
}
static __device__ __forceinline__ f32x2 pk_add(f32x2 a, f32x2 b) {
  f32x2 d;
  asm("v_pk_add_f32 %0, %1, %2" : "=v"(d) : "v"(a), "v"(b));
  return d;
}
static __device__ __forceinline__ float max3f(float a, float b, float c) {
  float d;
  asm("v_max3_f32 %0, %1, %2, %3" : "=v"(d) : "v"(a), "v"(b), "v"(c));
  return d;
}

// ---------------- fused f32 -> bf16 convert (8 elems/thread) ----------------
__global__ __launch_bounds__(256) void k_cvt_all(
    const float* __restrict__ x, const float* __restrict__ Wq,
    const float* __restrict__ Wk, const float* __restrict__ Wv,
    const float* __restrict__ Wo, unsigned short* __restrict__ xb,
    unsigned short* __restrict__ wb) {
  int bb = blockIdx.x;
  const float* src;
  unsigned short* dst;
  int i;
  if (bb < 2048) {
    src = x; dst = xb; i = bb * 256 + threadIdx.x;
  } else {
    int wsel = (bb - 2048) >> 9;
    src = (wsel == 0) ? Wq : (wsel == 1) ? Wk : (wsel == 2) ? Wv : Wo;
    dst = wb + (size_t)wsel * (KDIM * KDIM);
    i = ((bb - 2048) & 511) * 256 + threadIdx.x;
  }
  const float4* p = (const float4*)src + (size_t)i * 2;
  float4 a = p[0], b = p[1];
  u16x8 o;
  o[0] = f2bf(a.x); o[1] = f2bf(a.y); o[2] = f2bf(a.z); o[3] = f2bf(a.w);
  o[4] = f2bf(b.x); o[5] = f2bf(b.y); o[6] = f2bf(b.z); o[7] = f2bf(b.w);
  *((u16x8*)dst + i) = o;
}

// ---------------- GEMM C = A @ W^T (A:[M,K] bf16, W:[N,K] bf16) ----------------
// 128x128 tile, BK=64, XOR-swizzled LDS (16B block ^= row&7 via pre-swizzled
// global source), 4 waves (2x2), 16x16x32 MFMA, 32 MFMA per barrier-pair.
// MODE 0: bf16 out [M,N].  MODE 1: f32 out + bias.  MODE 2: bf16 out written
// transposed per-head: Vt[(b*NH+h)*HD + d][t]  (col = h*64+d, row = b*2048+t).
template <int MODE>
static __device__ __forceinline__ void gemm_body(
    const unsigned short* __restrict__ A, const unsigned short* __restrict__ W,
    unsigned short* __restrict__ Cb, float* __restrict__ Cf,
    const float* __restrict__ bias, int by, int bx,
    unsigned short* As, unsigned short* Bs) {
  const int K = KDIM, N = KDIM;
  int tid = threadIdx.x, lane = tid & 63, wid = tid >> 6;
  int r = lane & 15, g = lane >> 4;
  int wm = wid >> 1, wn = wid & 1;

  f32x4 acc[4][4];
#pragma unroll
  for (int m = 0; m < 4; ++m)
#pragma unroll
    for (int n = 0; n < 4; ++n) acc[m][n] = (f32x4){0.f, 0.f, 0.f, 0.f};

  const unsigned short* Ag = A + (size_t)(by * 128) * K;
  const unsigned short* Wg = W + (size_t)(bx * 128) * K;

  for (int k0 = 0; k0 < K; k0 += 64) {
#pragma unroll
    for (int it = 0; it < 4; ++it) {
      int base = it * 256 + wid * 64;  // chunk 0..1023; row=c>>3, blk=c&7
      int c = base + lane;
      int rr = c >> 3;
      int blk = (c & 7) ^ (rr & 7);    // pre-swizzled source
      gload_lds16(Ag + (size_t)rr * K + k0 + blk * 8, &As[base * 8]);
      gload_lds16(Wg + (size_t)rr * K + k0 + blk * 8, &Bs[base * 8]);
    }
    __syncthreads();
#pragma unroll
    for (int ks = 0; ks < 2; ++ks) {
      bf16x8 af[4], bf[4];
#pragma unroll
      for (int m = 0; m < 4; ++m) {
        int row = wm * 64 + m * 16 + r;
        af[m] = ld_frag(&As[row * 64 + ((ks * 4 + g) ^ (r & 7)) * 8]);
      }
#pragma unroll
      for (int n = 0; n < 4; ++n) {
        int row = wn * 64 + n * 16 + r;
        bf[n] = ld_frag(&Bs[row * 64 + ((ks * 4 + g) ^ (r & 7)) * 8]);
      }
      __builtin_amdgcn_s_setprio(1);
#pragma unroll
      for (int m = 0; m < 4; ++m)
#pragma unroll
        for (int n = 0; n < 4; ++n)
          acc[m][n] = __builtin_amdgcn_mfma_f32_16x16x32_bf16(af[m], bf[n], acc[m][n], 0, 0, 0);
      __builtin_amdgcn_s_setprio(0);
    }
    __syncthreads();
  }

#pragma unroll
  for (int m = 0; m < 4; ++m)
#pragma unroll
    for (int n = 0; n < 4; ++n) {
      int col = bx * 128 + wn * 64 + n * 16 + r;
      if (MODE == 2) {
        int hq = col >> 6, dq = col & 63;
        int row0 = by * 128 + wm * 64 + m * 16 + g * 4;
        int bq = row0 >> 11, tq = row0 & 2047;
        u16x4 pv;
#pragma unroll
        for (int j = 0; j < 4; ++j) pv[j] = f2bf(acc[m][n][j]);
        *(u16x4*)&Cb[(((size_t)(bq * NH + hq)) * HD + dq) * TB + tq] = pv;
      } else {
#pragma unroll
        for (int j = 0; j < 4; ++j) {
          int row = by * 128 + wm * 64 + m * 16 + g * 4 + j;
          if (MODE == 0)
            Cb[(size_t)row * N + col] = f2bf(acc[m][n][j]);
          else
            Cf[(size_t)row * N + col] = acc[m][n][j] + bias[col];
        }
      }
    }
}

__global__ __launch_bounds__(256) void k_gemm_qkv(
    const unsigned short* __restrict__ X,
    const unsigned short* __restrict__ Wq, const unsigned short* __restrict__ Wk,
    const unsigned short* __restrict__ Wv,
    unsigned short* __restrict__ Q, unsigned short* __restrict__ Kp,
    unsigned short* __restrict__ Vt) {
  __shared__ __align__(16) unsigned short As[8192];
  __shared__ __align__(16) unsigned short Bs[8192];
  int idx = blockIdx.x;            // 32 * 24
  int by = idx / 24, bxx = idx % 24;
  int which = bxx >> 3, bx = bxx & 7;
  if (which == 2) {
    gemm_body<2>(X, Wv, Vt, nullptr, nullptr, by, bx, As, Bs);
  } else {
    const unsigned short* W = which ? Wk : Wq;
    unsigned short* C = which ? Kp : Q;
    gemm_body<0>(X, W, C, nullptr, nullptr, by, bx, As, Bs);
  }
}

__global__ __launch_bounds__(256) void k_gemm_out(
    const unsigned short* __restrict__ AO, const unsigned short* __restrict__ Wo,
    float* __restrict__ out, const float* __restrict__ bias) {
  __shared__ __align__(16) unsigned short As[8192];
  __shared__ __align__(16) unsigned short Bs[8192];
  int by = blockIdx.x >> 3, bx = blockIdx.x & 7;
  gemm_body<1>(AO, Wo, nullptr, out, bias, by, bx, As, Bs);
}

// ---------------- flash attention (swapped QK^T, 32x32x16, in-block KV split) --
// grid: b*h*(T/128) blocks, 512 threads (8 waves). Wave w: qgroup wl=w&3 (32
// q-rows), half = w>>2 (KV tiles half*16..half*16+15). Merged at end via LDS.
__global__ __launch_bounds__(512, 4) void k_attn(
    const unsigned short* __restrict__ Q, const unsigned short* __restrict__ Kp,
    const unsigned short* __restrict__ Vt, unsigned short* __restrict__ AO) {
  __shared__ __align__(16) unsigned short Ks[2][2][4096];  // [half][buf][key][d]
  __shared__ __align__(16) unsigned short Vs[2][2][4096];  // [half][buf][d][key]

  int qt = blockIdx.x & 15, bh = blockIdx.x >> 4;
  int b = bh >> 4, h = bh & 15;
  int tid = threadIdx.x, lane = tid & 63, w = tid >> 6;
  int wl = w & 3, half = w >> 2;
  int q = lane & 31, hh = lane >> 5;
  const float LOG2E = 1.44269504f;
  const int HT = (TB / 64) / 2;  // 16 tiles per half

  const unsigned short* Qp =
      Q + ((size_t)(b * TB + qt * 128 + wl * 32 + q)) * KDIM + h * HD;
  bf16x8 qf[4];
#pragma unroll
  for (int f = 0; f < 4; ++f) qf[f] = ld_frag(&Qp[16 * f + 8 * hh]);

  f32x16 o0, o1;
#pragma unroll
  for (int i = 0; i < 16; ++i) { o0[i] = 0.f; o1[i] = 0.f; }
  float m_run = -1e30f, l_run = 0.f;

  const unsigned short* Kbase = Kp + (size_t)(b * TB) * KDIM + h * HD;
  const unsigned short* Vbase = Vt + (size_t)bh * HD * TB;

  auto stage = [&](int kt, int buf) {
#pragma unroll
    for (int it = 0; it < 2; ++it) {
      int base = it * 256 + wl * 64;
      int c = base + lane;
      int rr = c >> 3;
      int blk = (c & 7) ^ (rr & 7);   // pre-swizzled global source
      gload_lds16(Kbase + (size_t)(kt * 64 + rr) * KDIM + blk * 8,
                  &Ks[half][buf][base * 8]);
      gload_lds16(Vbase + (size_t)rr * TB + kt * 64 + blk * 8,
                  &Vs[half][buf][base * 8]);
    }
  };

  stage(half * HT, 0);
  __syncthreads();
  int cur = 0;

  for (int t = 0; t < HT; ++t) {
    if (t + 1 < HT) stage(half * HT + t + 1, cur ^ 1);

    // S^T = K_tile @ Q^T
    const unsigned short* Kc = &Ks[half][cur][0];
    f32x16 st[2];
    __builtin_amdgcn_s_setprio(1);
#pragma unroll
    for (int g = 0; g < 2; ++g) {
#pragma unroll
      for (int i = 0; i < 16; ++i) st[g][i] = 0.f;
#pragma unroll
      for (int f = 0; f < 4; ++f) {
        int row = g * 32 + q;
        int bl = (2 * f + hh) ^ (row & 7);
        bf16x8 kf = ld_frag(&Kc[row * 64 + bl * 8]);
        st[g] = __builtin_amdgcn_mfma_f32_32x32x16_bf16(kf, qf[f], st[g], 0, 0, 0);
      }
    }
    __builtin_amdgcn_s_setprio(0);

    // online softmax — max3 tree (17 ops, depth 4)
    float m0 = max3f(st[0][0], st[0][1], st[0][2]);
    float m1 = max3f(st[0][3], st[0][4], st[0][5]);
    float m2 = max3f(st[0][6], st[0][7], st[0][8]);
    float m3 = max3f(st[0][9], st[0][10], st[0][11]);
    float m4 = max3f(st[0][12], st[0][13], st[0][14]);
    float m5 = max3f(st[0][15], st[1][0], st[1][1]);
    float m6 = max3f(st[1][2], st[1][3], st[1][4]);
    float m7 = max3f(st[1][5], st[1][6], st[1][7]);
    float m8 = max3f(st[1][8], st[1][9], st[1][10]);
    float m9 = max3f(st[1][11], st[1][12], st[1][13]);
    float u0 = max3f(m0, m1, m2);
    float u1 = max3f(m3, m4, m5);
    float u2 = max3f(m6, m7, m8);
    float u3 = max3f(m9, st[1][14], st[1][15]);
    float pm = fmaxf(fmaxf(u0, u1), fmaxf(u2, u3));
    pm = fmaxf(pm, __shfl_xor(pm, 32));
    float spm = pm * 0.125f;
    if (!__all(spm <= m_run + 8.f)) {   // defer-max (T13)
      float mnew = fmaxf(m_run, spm);
      float sc = fast_exp2((m_run - mnew) * LOG2E);
      m_run = mnew;
      l_run *= sc;
#pragma unroll
      for (int p = 0; p < 16; ++p) {
        float scp = __shfl(sc, (p & 3) + 8 * (p >> 2) + 4 * hh);
        o0[p] *= scp;
        o1[p] *= scp;
      }
    }

    // P = exp(S - m) via packed fma + packed sum; bf16 fragments in-register
    float c1 = 0.125f * LOG2E, c2 = m_run * LOG2E;
    f32x2 c1v; c1v[0] = c1; c1v[1] = c1;
    f32x2 c2v; c2v[0] = -c2; c2v[1] = -c2;
    f32x2 rsv; rsv[0] = 0.f; rsv[1] = 0.f;
    bf16x8 pa[4];
#pragma unroll
    for (int g = 0; g < 2; ++g) {
      unsigned d[8];
#pragma unroll
      for (int i = 0; i < 8; ++i) {
        f32x2 p; p[0] = st[g][2 * i]; p[1] = st[g][2 * i + 1];
        p = pk_fma(p, c1v, c2v);
        f32x2 e; e[0] = fast_exp2(p[0]); e[1] = fast_exp2(p[1]);
        rsv = pk_add(rsv, e);
        d[i] = cvt_pk(e[0], e[1]);
      }
      u32x2 r1 = permswap(d[0], d[2]);
      u32x2 r2 = permswap(d[1], d[3]);
      u32x2 r3 = permswap(d[4], d[6]);
      u32x2 r4 = permswap(d[5], d[7]);
      u32x4 t0; t0[0] = r1.x; t0[1] = r2.x; t0[2] = r1.y; t0[3] = r2.y;
      u32x4 t1; t1[0] = r3.x; t1[1] = r4.x; t1[2] = r3.y; t1[3] = r4.y;
      pa[2 * g]     = __builtin_bit_cast(bf16x8, t0);
      pa[2 * g + 1] = __builtin_bit_cast(bf16x8, t1);
    }
    float rs = rsv[0] + rsv[1];
    rs += __shfl_xor(rs, 32);
    l_run += rs;

    // O += P @ V
    const unsigned short* Vc = &Vs[half][cur][0];
    __builtin_amdgcn_s_setprio(1);
#pragma unroll
    for (int s = 0; s < 4; ++s) {
      int bl = (2 * s + hh) ^ (q & 7);
      bf16x8 v0 = ld_frag(&Vc[q * 64 + bl * 8]);
      bf16x8 v1 = ld_frag(&Vc[(32 + q) * 64 + bl * 8]);
      o0 = __builtin_amdgcn_mfma_f32_32x32x16_bf16(pa[s], v0, o0, 0, 0, 0);
      o1 = __builtin_amdgcn_mfma_f32_32x32x16_bf16(pa[s], v1, o1, 0, 0, 0);
    }
    __builtin_amdgcn_s_setprio(0);

    __syncthreads();
    cur ^= 1;
  }

  // -------- merge halves via LDS (conflict-free [p][wl*64+lane] layout) --------
  float* Osw = (float*)&Vs[0][0][0];   // 32 KB = 32 x 256 floats
  float* MLb = (float*)&Ks[0][0][0];   // 256 floats
  if (half) {
#pragma unroll
    for (int p = 0; p < 16; ++p) {
      Osw[p * 256 + wl * 64 + lane]        = o0[p];
      Osw[(16 + p) * 256 + wl * 64 + lane] = o1[p];
    }
    if (!hh) {
      MLb[wl * 32 + q]       = m_run;
      MLb[128 + wl * 32 + q] = l_run;
    }
  }
  __syncthreads();
  if (!half) {
    float m2r = MLb[wl * 32 + q], l2 = MLb[128 + wl * 32 + q];
    float mm = fmaxf(m_run, m2r);
    float ea = fast_exp2((m_run - mm) * LOG2E);
    float eb = fast_exp2((m2r - mm) * LOG2E);
    float il = 1.f / (l_run * ea + l2 * eb);
#pragma unroll
    for (int p = 0; p < 16; ++p) {
      int qr = (p & 3) + 8 * (p >> 2) + 4 * hh;
      float a  = __shfl(ea, qr);
      float bb = __shfl(eb, qr);
      float ip = __shfl(il, qr);
      float v0 = (o0[p] * a + Osw[p * 256 + wl * 64 + lane] * bb) * ip;
      float v1 = (o1[p] * a + Osw[(16 + p) * 256 + wl * 64 + lane] * bb) * ip;
      int row = qt * 128 + wl * 32 + qr;
      size_t base = ((size_t)(b * TB + row)) * KDIM + h * HD;
      AO[base + q]      = f2bf(v0);
      AO[base + 32 + q] = f2bf(v1);
    }
  }
}

// ---------------- launch ----------------
extern "C" void kernel_launch(void* const* d_in, const int* in_sizes, int n_in,
                              void* d_out, int out_size, void* d_ws, size_t ws_size,
                              hipStream_t stream) {
  const float* x  = (const float*)d_in[0];
  const float* Wq = (const float*)d_in[1];
  const float* Wk = (const float*)d_in[2];
  const float* Wv = (const float*)d_in[3];
  const float* Wo = (const float*)d_in[4];
  const float* bo = (const float*)d_in[5];

  char* ws = (char*)d_ws;
  const size_t MB = 1 << 20;
  unsigned short* xb  = (unsigned short*)(ws + 0 * MB);   // 8 MiB
  unsigned short* wqb = (unsigned short*)(ws + 8 * MB);   // 4 x 2 MiB contiguous
  unsigned short* wkb = (unsigned short*)(ws + 10 * MB);
  unsigned short* wvb = (unsigned short*)(ws + 12 * MB);
  unsigned short* wob = (unsigned short*)(ws + 14 * MB);
  unsigned short* Qb  = (unsigned short*)(ws + 16 * MB);  // 8 MiB
  unsigned short* Kb  = (unsigned short*)(ws + 24 * MB);
  unsigned short* Vtb = (unsigned short*)(ws + 32 * MB);
  unsigned short* AOb = (unsigned short*)(ws + 40 * MB);  // ends at 48 MiB

  k_cvt_all<<<4096, 256, 0, stream>>>(x, Wq, Wk, Wv, Wo, xb, wqb);
  k_gemm_qkv<<<32 * 24, 256, 0, stream>>>(xb, wqb, wkb, wvb, Qb, Kb, Vtb);
  k_attn<<<512, 512, 0, stream>>>(Qb, Kb, Vtb, AOb);
  k_gemm_out<<<256, 256, 0, stream>>>(AOb, wob, (float*)d_out, bo);
}